// Round 19
// baseline (96.860 us; speedup 1.0000x reference)
//
#include <hip/hip_runtime.h>
#include <hip/hip_bf16.h>
#include <hip/hip_cooperative_groups.h>

namespace cg = cooperative_groups;

// VQ-VAE vector quantizer, MI355X — cooperative single-dispatch R15.
// [k_all, coop, 256x512, 1/CU]:
//   pre-sync : blocks 0..31 prep emb -> PLAIN fp8 E (x512) + cn (ws);
//              ALL blocks issue lat HBM loads + build A-frags/row-norms in regs
//   grid.sync
//   post-sync: reg-stage E (L2) -> swizzled LDS; phase B sweep of 1024 codes;
//              butterfly; gather q=emb[k*] -> [B,D,H,W]; loss atomicAdd
// Fallback (coop launch error): R15's k_prep + k_fused, 2 dispatches.

typedef __attribute__((ext_vector_type(4))) float f32x4;

#define WS_E 0u          // fp8 PLAIN [1024][128] = 131072
#define WS_C 131072u     // f32 cn[1024]          = 4096

#define LOSS_SCALE (1.25f / 4194304.0f)
#define NEG2_INV_LAMBDA (-2.0f / 512.0f)

static __device__ inline unsigned cvt4_fp8(float a, float b, float c, float d) {
    int v = __builtin_amdgcn_cvt_pk_fp8_f32(a, b, 0, false);
    v = __builtin_amdgcn_cvt_pk_fp8_f32(c, d, v, true);
    return (unsigned)v;
}

// ================= cooperative fused kernel =================
// LDS: E @0 (128K, swz) | C @131072 (4K) | win @135168 (512) | rs @135680 (32)
__global__ __launch_bounds__(512, 1) void k_all(const float* __restrict__ lat,
                                                const float* __restrict__ emb,
                                                char* __restrict__ Eb,
                                                float* __restrict__ cn,
                                                float* __restrict__ outq,
                                                float* __restrict__ loss) {
    __shared__ __align__(16) char lds[135712];
    char*  ldsE = lds;
    float* ldsC = (float*)(lds + 131072);
    int*   win  = (int*)  (lds + 135168);
    float* rs   = (float*)(lds + 135680);

    const int t = threadIdx.x, bm = blockIdx.x;     // 256 blocks
    const int lane = t & 63, w = t >> 6;            // 8 waves
    const int l15 = lane & 15, lg = lane >> 4;
    const int b = bm >> 3, hw0 = (bm & 7) << 7;     // 128 rows

    // ---- pre-sync prep: blocks 0..31 build E + cn in ws ----
    if (bm < 32) {
        int g = (bm << 9) + t;                      // 0..16383
        int row = g >> 4, c = g & 15;
        const float4* ep = (const float4*)(emb + ((size_t)row << 7) + (c << 3));
        float4 e0 = ep[0], e1 = ep[1];
        float s = e0.x*e0.x + e0.y*e0.y + e0.z*e0.z + e0.w*e0.w
                + e1.x*e1.x + e1.y*e1.y + e1.z*e1.z + e1.w*e1.w;
#pragma unroll
        for (int mk = 1; mk < 16; mk <<= 1) s += __shfl_xor(s, mk);
        if (c == 0) cn[row] = s;
        uint2 v;
        v.x = cvt4_fp8(512.f*e0.x, 512.f*e0.y, 512.f*e0.z, 512.f*e0.w);
        v.y = cvt4_fp8(512.f*e1.x, 512.f*e1.y, 512.f*e1.z, 512.f*e1.w);
        *(uint2*)(Eb + row * 128 + c * 8) = v;
        if (g == 0) loss[0] = 0.f;
    }

    // ---- pre-sync: lat HBM loads + A-frags + row norms (indep. of prep) ----
    const float* lp = lat + ((size_t)b << 17) + hw0 + (w << 4) + l15;
    float xv[4][8];
#pragma unroll
    for (int ks = 0; ks < 4; ++ks)
#pragma unroll
        for (int j = 0; j < 8; ++j)
            xv[ks][j] = lp[(size_t)(ks * 32 + lg * 8 + j) << 10];

    float rn = 0.f;
    long av[4];
#pragma unroll
    for (int ks = 0; ks < 4; ++ks) {
#pragma unroll
        for (int j = 0; j < 8; ++j) rn = fmaf(xv[ks][j], xv[ks][j], rn);
        unsigned lo = cvt4_fp8(xv[ks][0], xv[ks][1], xv[ks][2], xv[ks][3]);
        unsigned hi = cvt4_fp8(xv[ks][4], xv[ks][5], xv[ks][6], xv[ks][7]);
        av[ks] = (long)(((unsigned long long)hi << 32) | lo);
    }

    __threadfence();
    cg::this_grid().sync();          // E + cn visible device-wide

    // ---- stage E from ws (L2/L3) -> swizzled LDS; cn -> LDS ----
#pragma unroll
    for (int i = 0; i < 16; ++i) {
        int goff = i * 8192 + t * 16;
        uint4 u = *(const uint4*)(Eb + goff);
        int row = goff >> 7, c16 = (goff >> 4) & 7;
        *(uint4*)(ldsE + row * 128 + ((c16 << 4) ^ ((row & 7) << 4))) = u;
    }
    if (t < 256) {
        uint4 cnr = *(const uint4*)((const char*)cn + t * 16);
        *(uint4*)((char*)ldsC + t * 16) = cnr;
    }
    __syncthreads();                 // E + cn resident

    // ---- phase B: barrier-free sweep of all 1024 codes from LDS ----
    float run_s[4]; int run_i[4];
#pragma unroll
    for (int r = 0; r < 4; ++r) { run_s[r] = 3.0e38f; run_i[r] = 0; }

    for (int ct = 0; ct < 8; ++ct) {
        float cnv[8];
#pragma unroll
        for (int c = 0; c < 8; ++c) cnv[c] = ldsC[(ct << 7) + (c << 4) + l15];

        f32x4 acc[8];
#pragma unroll
        for (int c = 0; c < 8; ++c) acc[c] = (f32x4){0.f, 0.f, 0.f, 0.f};
#pragma unroll
        for (int ks = 0; ks < 4; ++ks) {
            long bv[8];
#pragma unroll
            for (int c = 0; c < 8; ++c) {
                int rr = (ct << 7) + (c << 4) + l15;
                bv[c] = *(const long*)(ldsE + rr * 128 +
                         ((ks * 32 + lg * 8) ^ ((rr & 7) << 4)));
            }
#pragma unroll
            for (int c = 0; c < 8; ++c)
                acc[c] = __builtin_amdgcn_mfma_f32_16x16x32_fp8_fp8(av[ks], bv[c], acc[c], 0, 0, 0);
        }
#pragma unroll
        for (int c = 0; c < 8; ++c) {
            int kg = (ct << 7) + (c << 4) + l15;
#pragma unroll
            for (int r = 0; r < 4; ++r) {
                float s = fmaf(NEG2_INV_LAMBDA, acc[c][r], cnv[c]);
                if (s < run_s[r]) { run_s[r] = s; run_i[r] = kg; }
            }
        }
    }

    // ---- butterfly over 16 code-lanes; win + loss partials ----
    float bs = 0.f;
#pragma unroll
    for (int r = 0; r < 4; ++r) {
        float s = run_s[r]; int bi = run_i[r];
#pragma unroll
        for (int mask = 1; mask < 16; mask <<= 1) {
            float os = __shfl_xor(s, mask);
            int   oi = __shfl_xor(bi, mask);
            if (os < s || (os == s && oi < bi)) { s = os; bi = oi; }
        }
        if (l15 == 0) {
            win[(w << 4) + (lg << 2) + r] = bi;
            bs += s;
        }
    }
    {
        float v = ((l15 == 0) ? bs : 0.f) + rn;
#pragma unroll
        for (int m = 1; m < 64; m <<= 1) v += __shfl_xor(v, m);
        if (lane == 0) rs[w] = v;
    }
    __syncthreads();
    if (t == 0) {
        float v = rs[0] + rs[1] + rs[2] + rs[3] + rs[4] + rs[5] + rs[6] + rs[7];
        atomicAdd(loss, v * LOSS_SCALE);
    }

    // ---- gather q = emb[k*] fp32, store [B,D,H,W] coalesced ----
    {
        const int rowl = t & 127, dg = t >> 7;
        const int bi = win[rowl];
        const float4* eg = (const float4*)(emb + ((size_t)bi << 7) + (dg << 5));
        float* ob = outq + ((size_t)b << 17) + ((size_t)(dg << 5) << 10) + hw0 + rowl;
#pragma unroll
        for (int jj = 0; jj < 8; ++jj) {
            float4 v = eg[jj];
            ob[(size_t)(jj * 4 + 0) << 10] = v.x;
            ob[(size_t)(jj * 4 + 1) << 10] = v.y;
            ob[(size_t)(jj * 4 + 2) << 10] = v.z;
            ob[(size_t)(jj * 4 + 3) << 10] = v.w;
        }
    }
}

// ================= fallback: R15 two-dispatch =================
__global__ __launch_bounds__(256) void k_prep(const float* __restrict__ emb,
                                              char* __restrict__ Eb,
                                              float* __restrict__ cn,
                                              float* __restrict__ loss) {
    const int t = threadIdx.x;
    const int row = (blockIdx.x << 4) + (t >> 4), c = t & 15;
    const float4* ep = (const float4*)(emb + ((size_t)row << 7) + (c << 3));
    float4 e0 = ep[0], e1 = ep[1];
    float s = e0.x*e0.x + e0.y*e0.y + e0.z*e0.z + e0.w*e0.w
            + e1.x*e1.x + e1.y*e1.y + e1.z*e1.z + e1.w*e1.w;
#pragma unroll
    for (int m = 1; m < 16; m <<= 1) s += __shfl_xor(s, m);
    if (c == 0) cn[row] = s;
    uint2 v;
    v.x = cvt4_fp8(512.f*e0.x, 512.f*e0.y, 512.f*e0.z, 512.f*e0.w);
    v.y = cvt4_fp8(512.f*e1.x, 512.f*e1.y, 512.f*e1.z, 512.f*e1.w);
    *(uint2*)(Eb + row * 128 + c * 8) = v;
    if (blockIdx.x == 0 && t == 0) loss[0] = 0.f;
}

__global__ __launch_bounds__(512, 1) void k_fused(const float* __restrict__ lat,
                                                  const float* __restrict__ emb,
                                                  const char* __restrict__ Eb,
                                                  const float* __restrict__ cn,
                                                  float* __restrict__ outq,
                                                  float* __restrict__ loss) {
    __shared__ __align__(16) char lds[135712];
    char*  ldsE = lds;
    float* ldsC = (float*)(lds + 131072);
    int*   win  = (int*)  (lds + 135168);
    float* rs   = (float*)(lds + 135680);

    const int t = threadIdx.x, bm = blockIdx.x;
    const int lane = t & 63, w = t >> 6;
    const int l15 = lane & 15, lg = lane >> 4;
    const int b = bm >> 3, hw0 = (bm & 7) << 7;

    uint4 ur[16];
#pragma unroll
    for (int i = 0; i < 16; ++i)
        ur[i] = *(const uint4*)(Eb + i * 8192 + t * 16);
    uint4 cnr = (t < 256) ? *(const uint4*)((const char*)cn + t * 16)
                          : (uint4){0, 0, 0, 0};

    const float* lp = lat + ((size_t)b << 17) + hw0 + (w << 4) + l15;
    float xv[4][8];
#pragma unroll
    for (int ks = 0; ks < 4; ++ks)
#pragma unroll
        for (int j = 0; j < 8; ++j)
            xv[ks][j] = lp[(size_t)(ks * 32 + lg * 8 + j) << 10];

#pragma unroll
    for (int i = 0; i < 16; ++i) {
        int goff = i * 8192 + t * 16;
        int row = goff >> 7, c16 = (goff >> 4) & 7;
        *(uint4*)(ldsE + row * 128 + ((c16 << 4) ^ ((row & 7) << 4))) = ur[i];
    }
    if (t < 256) *(uint4*)((char*)ldsC + t * 16) = cnr;

    float rn = 0.f;
    long av[4];
#pragma unroll
    for (int ks = 0; ks < 4; ++ks) {
#pragma unroll
        for (int j = 0; j < 8; ++j) rn = fmaf(xv[ks][j], xv[ks][j], rn);
        unsigned lo = cvt4_fp8(xv[ks][0], xv[ks][1], xv[ks][2], xv[ks][3]);
        unsigned hi = cvt4_fp8(xv[ks][4], xv[ks][5], xv[ks][6], xv[ks][7]);
        av[ks] = (long)(((unsigned long long)hi << 32) | lo);
    }
    __syncthreads();

    float run_s[4]; int run_i[4];
#pragma unroll
    for (int r = 0; r < 4; ++r) { run_s[r] = 3.0e38f; run_i[r] = 0; }

    for (int ct = 0; ct < 8; ++ct) {
        float cnv[8];
#pragma unroll
        for (int c = 0; c < 8; ++c) cnv[c] = ldsC[(ct << 7) + (c << 4) + l15];
        f32x4 acc[8];
#pragma unroll
        for (int c = 0; c < 8; ++c) acc[c] = (f32x4){0.f, 0.f, 0.f, 0.f};
#pragma unroll
        for (int ks = 0; ks < 4; ++ks) {
            long bv[8];
#pragma unroll
            for (int c = 0; c < 8; ++c) {
                int rr = (ct << 7) + (c << 4) + l15;
                bv[c] = *(const long*)(ldsE + rr * 128 +
                         ((ks * 32 + lg * 8) ^ ((rr & 7) << 4)));
            }
#pragma unroll
            for (int c = 0; c < 8; ++c)
                acc[c] = __builtin_amdgcn_mfma_f32_16x16x32_fp8_fp8(av[ks], bv[c], acc[c], 0, 0, 0);
        }
#pragma unroll
        for (int c = 0; c < 8; ++c) {
            int kg = (ct << 7) + (c << 4) + l15;
#pragma unroll
            for (int r = 0; r < 4; ++r) {
                float s = fmaf(NEG2_INV_LAMBDA, acc[c][r], cnv[c]);
                if (s < run_s[r]) { run_s[r] = s; run_i[r] = kg; }
            }
        }
    }

    float bs = 0.f;
#pragma unroll
    for (int r = 0; r < 4; ++r) {
        float s = run_s[r]; int bi = run_i[r];
#pragma unroll
        for (int mask = 1; mask < 16; mask <<= 1) {
            float os = __shfl_xor(s, mask);
            int   oi = __shfl_xor(bi, mask);
            if (os < s || (os == s && oi < bi)) { s = os; bi = oi; }
        }
        if (l15 == 0) { win[(w << 4) + (lg << 2) + r] = bi; bs += s; }
    }
    {
        float v = ((l15 == 0) ? bs : 0.f) + rn;
#pragma unroll
        for (int m = 1; m < 64; m <<= 1) v += __shfl_xor(v, m);
        if (lane == 0) rs[w] = v;
    }
    __syncthreads();
    if (t == 0) {
        float v = rs[0] + rs[1] + rs[2] + rs[3] + rs[4] + rs[5] + rs[6] + rs[7];
        atomicAdd(loss, v * LOSS_SCALE);
    }
    {
        const int rowl = t & 127, dg = t >> 7;
        const int bi = win[rowl];
        const float4* eg = (const float4*)(emb + ((size_t)bi << 7) + (dg << 5));
        float* ob = outq + ((size_t)b << 17) + ((size_t)(dg << 5) << 10) + hw0 + rowl;
#pragma unroll
        for (int jj = 0; jj < 8; ++jj) {
            float4 v = eg[jj];
            ob[(size_t)(jj * 4 + 0) << 10] = v.x;
            ob[(size_t)(jj * 4 + 1) << 10] = v.y;
            ob[(size_t)(jj * 4 + 2) << 10] = v.z;
            ob[(size_t)(jj * 4 + 3) << 10] = v.w;
        }
    }
}

extern "C" void kernel_launch(void* const* d_in, const int* in_sizes, int n_in,
                              void* d_out, int out_size, void* d_ws, size_t ws_size,
                              hipStream_t stream) {
    const float* lat = (const float*)d_in[0];   // [32,128,32,32]
    const float* emb = (const float*)d_in[1];   // [1024,128]
    float* out = (float*)d_out;                 // q (4194304) + vq_loss (1)
    char* ws = (char*)d_ws;
    char*  E    = ws + WS_E;
    float* cn   = (float*)(ws + WS_C);
    float* loss = out + 4194304;

    void* args[] = {(void*)&lat, (void*)&emb, (void*)&E,
                    (void*)&cn, (void*)&out, (void*)&loss};
    hipError_t err = hipLaunchCooperativeKernel(
        reinterpret_cast<void*>(k_all), dim3(256), dim3(512), args, 0, stream);
    if (err != hipSuccess) {
        // fallback: proven 2-dispatch R15 path
        k_prep <<<64,  256, 0, stream>>>(emb, E, cn, loss);
        k_fused<<<256, 512, 0, stream>>>(lat, emb, E, cn, out, loss);
    }
}

// Round 20
// 40.029 us; speedup vs baseline: 2.4197x; 2.4197x over previous
//
#include <hip/hip_runtime.h>
#include <hip/hip_bf16.h>

// VQ-VAE vector quantizer, MI355X — fragment-major E, zero-LDS hot loop.
// [k_prep] 64 blocks: emb -> FRAG-MAJOR fp8 E (x512): fragment (tile,ks) is a
//          dense 512B block laid out lane-linear for the 16x16x32 B-operand
//          (byte (tile*4+ks)*512 + (lg*16+l15)*8 = E[tile*16+l15][ks*32+lg*8]);
//          + cn=||e||^2 fp32; loss=0.
// [k_main] 1024 blocks x 256thr (4/CU, 16 waves/CU): block = 32 rows of one b.
//   wave (rw=w&1, ch=w>>1) = rows [16rw,+16) x codes [512ch,+512).
//   - A-frags direct from lat (regs, cvt fp8); row-norms free (ch==0)
//   - hot loop: per c-tile 4 COALESCED 512B loads (uint2/lane, L2-served,
//     R14 fix: was 16x32B scattered) -> 4 MFMA; fold s = cn-(2/512)t;
//     unroll 4 -> 4 indep acc chains; ZERO LDS/barriers in loop
//   - 16-lane butterfly -> 2-way code-half merge -> win
//   - gather q=emb[k*] fp32 -> [B,D,H,W], one loss atomicAdd per block

typedef __attribute__((ext_vector_type(4))) float f32x4;

// workspace layout (bytes)
#define WS_E 0u          // fp8 FRAG-MAJOR [64 tiles][4 ks][512B] = 131072
#define WS_C 131072u     // f32 cn[1024]                          = 4096

#define LOSS_SCALE (1.25f / 4194304.0f)
#define NEG2_INV_LAMBDA (-2.0f / 512.0f)

static __device__ inline unsigned cvt4_fp8(float a, float b, float c, float d) {
    int v = __builtin_amdgcn_cvt_pk_fp8_f32(a, b, 0, false);
    v = __builtin_amdgcn_cvt_pk_fp8_f32(c, d, v, true);
    return (unsigned)v;
}

// ---------------- codebook prep (FRAG-MAJOR layout) ----------------
__global__ __launch_bounds__(256) void k_prep(const float* __restrict__ emb,
                                              char* __restrict__ Eb,
                                              float* __restrict__ cn,
                                              float* __restrict__ loss) {
    const int t = threadIdx.x;
    const int row = (blockIdx.x << 4) + (t >> 4), c = t & 15;   // c: 8-float grp
    const float4* ep = (const float4*)(emb + ((size_t)row << 7) + (c << 3));
    float4 e0 = ep[0], e1 = ep[1];
    float s = e0.x*e0.x + e0.y*e0.y + e0.z*e0.z + e0.w*e0.w
            + e1.x*e1.x + e1.y*e1.y + e1.z*e1.z + e1.w*e1.w;
#pragma unroll
    for (int m = 1; m < 16; m <<= 1) s += __shfl_xor(s, m);
    if (c == 0) cn[row] = s;
    uint2 v;
    v.x = cvt4_fp8(512.f*e0.x, 512.f*e0.y, 512.f*e0.z, 512.f*e0.w);
    v.y = cvt4_fp8(512.f*e1.x, 512.f*e1.y, 512.f*e1.z, 512.f*e1.w);
    // frag-major dst: tile=row>>4, l15=row&15, ks=c>>2, lg=c&3
    const int tile = row >> 4, l15r = row & 15, ks = c >> 2, lgr = c & 3;
    *(uint2*)(Eb + ((tile << 2) + ks) * 512 + ((lgr << 4) + l15r) * 8) = v;
    if (blockIdx.x == 0 && t == 0) loss[0] = 0.f;
}

// ---------------- main: frag-major zero-LDS scoring ----------------
__global__ __launch_bounds__(256, 4) void k_main(const float* __restrict__ lat,
                                                 const float* __restrict__ emb,
                                                 const char* __restrict__ Eb,
                                                 const float* __restrict__ cn,
                                                 float* __restrict__ outq,
                                                 float* __restrict__ loss) {
    __shared__ float ms[64];     // [4 waves][16 rows]
    __shared__ int   mi[64];
    __shared__ int   win[32];
    __shared__ float rs[2];

    const int t = threadIdx.x, bm = blockIdx.x;   // 1024 blocks
    const int lane = t & 63, w = t >> 6;          // 4 waves
    const int l15 = lane & 15, lg = lane >> 4;
    const int b = bm >> 5, hw0 = (bm & 31) << 5;  // 32 rows/block
    const int rw = w & 1, ch = w >> 1;            // row-half, code-half

    // ---- A-frags direct from lat (regs) + row-norm ----
    const float* lp = lat + ((size_t)b << 17) + hw0 + (rw << 4) + l15;
    float xv[4][8];
#pragma unroll
    for (int ks = 0; ks < 4; ++ks)
#pragma unroll
        for (int j = 0; j < 8; ++j)
            xv[ks][j] = lp[(size_t)(ks * 32 + lg * 8 + j) << 10];

    float rn = 0.f;
    long av[4];
#pragma unroll
    for (int ks = 0; ks < 4; ++ks) {
#pragma unroll
        for (int j = 0; j < 8; ++j) rn = fmaf(xv[ks][j], xv[ks][j], rn);
        unsigned lo = cvt4_fp8(xv[ks][0], xv[ks][1], xv[ks][2], xv[ks][3]);
        unsigned hi = cvt4_fp8(xv[ks][4], xv[ks][5], xv[ks][6], xv[ks][7]);
        av[ks] = (long)(((unsigned long long)hi << 32) | lo);
    }

    // ---- hot loop: 32 c-tiles of this code-half; coalesced frag loads ----
    float run_s[4]; int run_i[4];
#pragma unroll
    for (int r = 0; r < 4; ++r) { run_s[r] = 3.0e38f; run_i[r] = 0; }

    const char*  Ef  = Eb + ((size_t)ch << 16);   // half = 32 tiles * 2KB
    const float* cnb = cn + (ch << 9);

#pragma unroll 4
    for (int ct = 0; ct < 32; ++ct) {
        const char* fp8b = Ef + (ct << 11) + lane * 8;   // dense 512B frags
        long bv0 = *(const long*)(fp8b);
        long bv1 = *(const long*)(fp8b + 512);
        long bv2 = *(const long*)(fp8b + 1024);
        long bv3 = *(const long*)(fp8b + 1536);
        const float cv = cnb[(ct << 4) + l15];

        f32x4 acc = (f32x4){0.f, 0.f, 0.f, 0.f};
        acc = __builtin_amdgcn_mfma_f32_16x16x32_fp8_fp8(av[0], bv0, acc, 0, 0, 0);
        acc = __builtin_amdgcn_mfma_f32_16x16x32_fp8_fp8(av[1], bv1, acc, 0, 0, 0);
        acc = __builtin_amdgcn_mfma_f32_16x16x32_fp8_fp8(av[2], bv2, acc, 0, 0, 0);
        acc = __builtin_amdgcn_mfma_f32_16x16x32_fp8_fp8(av[3], bv3, acc, 0, 0, 0);

        const int kg = (ch << 9) + (ct << 4) + l15;      // global code idx
#pragma unroll
        for (int r = 0; r < 4; ++r) {                    // C row = lg*4+r (img)
            float s = fmaf(NEG2_INV_LAMBDA, acc[r], cv);
            if (s < run_s[r]) { run_s[r] = s; run_i[r] = kg; }
        }
    }

    // ---- 16-lane butterfly over codes; per-wave winners to LDS ----
#pragma unroll
    for (int r = 0; r < 4; ++r) {
        float s = run_s[r]; int bi = run_i[r];
#pragma unroll
        for (int mask = 1; mask < 16; mask <<= 1) {
            float os = __shfl_xor(s, mask);
            int   oi = __shfl_xor(bi, mask);
            if (os < s || (os == s && oi < bi)) { s = os; bi = oi; }
        }
        if (l15 == 0) {
            ms[(w << 4) + (lg << 2) + r] = s;
            mi[(w << 4) + (lg << 2) + r] = bi;
        }
    }
    {   // row-norm partials: ch==0 waves cover each row once
#pragma unroll
        for (int m = 1; m < 64; m <<= 1) rn += __shfl_xor(rn, m);
        if (lane == 0 && ch == 0) rs[rw] = rn;
    }
    __syncthreads();

    // ---- wave 0: 2-way code-half merge + win + loss ----
    if (w == 0) {
        float bs = 0.f;
        if (lane < 32) {
            const int rh = lane >> 4, i16 = lane & 15;
            float s0 = ms[(rh << 4) + i16];        int i0 = mi[(rh << 4) + i16];
            float s1 = ms[((2 + rh) << 4) + i16];  int i1 = mi[((2 + rh) << 4) + i16];
            if (s1 < s0 || (s1 == s0 && i1 < i0)) { s0 = s1; i0 = i1; }
            win[lane] = i0;
            bs = s0;
        }
        float v = (lane < 32) ? bs : 0.f;
        if (lane < 2) v += rs[lane];
#pragma unroll
        for (int m = 1; m < 64; m <<= 1) v += __shfl_xor(v, m);
        if (lane == 0) atomicAdd(loss, v * LOSS_SCALE);
    }
    __syncthreads();

    // ---- gather q = emb[k*] fp32, store [B,D,H,W] coalesced ----
    {
        const int rowl = t & 31, dg = t >> 5;      // 8 dgrps x 16 d
        const int bi = win[rowl];
        const float4* eg = (const float4*)(emb + ((size_t)bi << 7) + (dg << 4));
        float* ob = outq + ((size_t)b << 17) + ((size_t)(dg << 4) << 10) + hw0 + rowl;
#pragma unroll
        for (int jj = 0; jj < 4; ++jj) {
            float4 v = eg[jj];
            ob[(size_t)(jj * 4 + 0) << 10] = v.x;
            ob[(size_t)(jj * 4 + 1) << 10] = v.y;
            ob[(size_t)(jj * 4 + 2) << 10] = v.z;
            ob[(size_t)(jj * 4 + 3) << 10] = v.w;
        }
    }
}

extern "C" void kernel_launch(void* const* d_in, const int* in_sizes, int n_in,
                              void* d_out, int out_size, void* d_ws, size_t ws_size,
                              hipStream_t stream) {
    const float* lat = (const float*)d_in[0];   // [32,128,32,32]
    const float* emb = (const float*)d_in[1];   // [1024,128]
    float* out = (float*)d_out;                 // q (4194304) + vq_loss (1)
    char* ws = (char*)d_ws;
    char*  E    = ws + WS_E;
    float* cn   = (float*)(ws + WS_C);
    float* loss = out + 4194304;

    k_prep<<<64,   256, 0, stream>>>(emb, E, cn, loss);
    k_main<<<1024, 256, 0, stream>>>(lat, emb, E, cn, out, loss);
}

// Round 21
// 30.646 us; speedup vs baseline: 3.1606x; 1.3062x over previous
//
#include <hip/hip_runtime.h>
#include <hip/hip_bf16.h>

// VQ-VAE vector quantizer, MI355X — FINAL: R13 champion (E-resident single-pass).
// Best measured: 30.69 us, absmax 1.95e-3 (threshold 2.5e-2).
// [k_prep]  64 blocks: emb -> swizzled fp8 E (x512) + cn=||e||^2 fp32; loss=0
// [k_fused] 256 blocks x 512thr (1/CU, 8 waves): block owns 128 hw rows of one b.
//   - stage ENTIRE fp8 E image (128KB) into LDS once (global_load_lds w16),
//     chunk order rotated by (blockIdx & 15)
//   - A-frags direct from lat (regs, cvt fp8); row-norms in the same pass
//   - phase B barrier-free: wave owns 16 rows, sweeps 1024 codes from LDS,
//     8 independent acc chains; fp32 fold s = cn - (2/512)*t
//   - in-wave butterfly, gather q=emb[k*] fp32 -> [B,D,H,W], 1 loss atomic/block
// Loss identity: sum||q-x||^2 = sum(min-score) + sum(x^2)  (exact in fp32).

typedef __attribute__((ext_vector_type(4))) float f32x4;

// workspace layout (bytes)
#define WS_E 0u          // fp8 swz [1024][128] = 131072
#define WS_C 131072u     // f32 cn[1024]        = 4096

#define LOSS_SCALE (1.25f / 4194304.0f)
#define NEG2_INV_LAMBDA (-2.0f / 512.0f)

static __device__ inline unsigned cvt4_fp8(float a, float b, float c, float d) {
    int v = __builtin_amdgcn_cvt_pk_fp8_f32(a, b, 0, false);
    v = __builtin_amdgcn_cvt_pk_fp8_f32(c, d, v, true);
    return (unsigned)v;
}

static __device__ inline void gload_lds16(const void* g, void* l) {
    __builtin_amdgcn_global_load_lds(
        (const __attribute__((address_space(1))) unsigned int*)g,
        (__attribute__((address_space(3))) unsigned int*)l, 16, 0, 0);
}

// ---------------- codebook prep ----------------
__global__ __launch_bounds__(256) void k_prep(const float* __restrict__ emb,
                                              char* __restrict__ Eb,
                                              float* __restrict__ cn,
                                              float* __restrict__ loss) {
    const int t = threadIdx.x;
    const int row = (blockIdx.x << 4) + (t >> 4), c = t & 15;
    const float4* ep = (const float4*)(emb + ((size_t)row << 7) + (c << 3));
    float4 e0 = ep[0], e1 = ep[1];
    float s = e0.x*e0.x + e0.y*e0.y + e0.z*e0.z + e0.w*e0.w
            + e1.x*e1.x + e1.y*e1.y + e1.z*e1.z + e1.w*e1.w;
#pragma unroll
    for (int m = 1; m < 16; m <<= 1) s += __shfl_xor(s, m);
    if (c == 0) cn[row] = s;
    uint2 v;
    v.x = cvt4_fp8(512.f*e0.x, 512.f*e0.y, 512.f*e0.z, 512.f*e0.w);
    v.y = cvt4_fp8(512.f*e1.x, 512.f*e1.y, 512.f*e1.z, 512.f*e1.w);
    *(uint2*)(Eb + row * 128 + ((c * 8) ^ ((row & 7) << 4))) = v;
    if (blockIdx.x == 0 && t == 0) loss[0] = 0.f;
}

// ---------------- fused: E-resident scoring + gather ----------------
// LDS: E @0 (128K) | win @131072 (512B) | rs @131584 (32B) = 131616 B.
__global__ __launch_bounds__(512, 1) void k_fused(const float* __restrict__ lat,
                                                  const float* __restrict__ emb,
                                                  const char* __restrict__ Eb,
                                                  const float* __restrict__ cn,
                                                  float* __restrict__ outq,
                                                  float* __restrict__ loss) {
    __shared__ char lds[131616];
    char*  ldsE = lds;                       // fp8 swz [1024][128]
    int*   win  = (int*)  (lds + 131072);    // [128]
    float* rs   = (float*)(lds + 131584);    // [8]

    const int t = threadIdx.x, bm = blockIdx.x;     // 256 blocks
    const int lane = t & 63, w = t >> 6;            // 8 waves
    const int l15 = lane & 15, lg = lane >> 4;
    const int b = bm >> 3, hw0 = (bm & 7) << 7;     // 128 rows, line-aligned
    const int rot = bm & 15;                        // stagger phase

    // ---- stage full E image (128 KB), chunk order rotated per block ----
#pragma unroll
    for (int i = 0; i < 16; ++i) {
        int chunk = (i + rot) & 15;                 // 16 chunks of 8 KB
        int base = chunk * 8192 + (w << 10);        // wave-uniform byte base
        gload_lds16(Eb + base + lane * 16, ldsE + base);
    }

    // ---- A-frags direct from lat (regs), row-norm partial in same pass ----
    const float* lp = lat + ((size_t)b << 17) + hw0 + (w << 4) + l15;
    float xv[4][8];
#pragma unroll
    for (int ks = 0; ks < 4; ++ks)
#pragma unroll
        for (int j = 0; j < 8; ++j)
            xv[ks][j] = lp[(size_t)(ks * 32 + lg * 8 + j) << 10];

    float rn = 0.f;
    long av[4];
#pragma unroll
    for (int ks = 0; ks < 4; ++ks) {
#pragma unroll
        for (int j = 0; j < 8; ++j) rn = fmaf(xv[ks][j], xv[ks][j], rn);
        unsigned lo = cvt4_fp8(xv[ks][0], xv[ks][1], xv[ks][2], xv[ks][3]);
        unsigned hi = cvt4_fp8(xv[ks][4], xv[ks][5], xv[ks][6], xv[ks][7]);
        av[ks] = (long)(((unsigned long long)hi << 32) | lo);
    }
    __syncthreads();                 // E image resident (vmcnt drained)

    // ---- phase B: barrier-free sweep of all 1024 codes from LDS ----
    float run_s[4]; int run_i[4];
#pragma unroll
    for (int r = 0; r < 4; ++r) { run_s[r] = 3.0e38f; run_i[r] = 0; }

    for (int ct = 0; ct < 8; ++ct) {
        float cnv[8];
#pragma unroll
        for (int c = 0; c < 8; ++c) cnv[c] = cn[(ct << 7) + (c << 4) + l15];

        f32x4 acc[8];
#pragma unroll
        for (int c = 0; c < 8; ++c) acc[c] = (f32x4){0.f, 0.f, 0.f, 0.f};
#pragma unroll
        for (int ks = 0; ks < 4; ++ks) {
            long bv[8];
#pragma unroll
            for (int c = 0; c < 8; ++c) {
                int rr = (ct << 7) + (c << 4) + l15;
                bv[c] = *(const long*)(ldsE + rr * 128 +
                         ((ks * 32 + lg * 8) ^ ((rr & 7) << 4)));
            }
#pragma unroll
            for (int c = 0; c < 8; ++c)
                acc[c] = __builtin_amdgcn_mfma_f32_16x16x32_fp8_fp8(av[ks], bv[c], acc[c], 0, 0, 0);
        }
#pragma unroll
        for (int c = 0; c < 8; ++c) {
            int kg = (ct << 7) + (c << 4) + l15;
#pragma unroll
            for (int r = 0; r < 4; ++r) {
                float s = fmaf(NEG2_INV_LAMBDA, acc[c][r], cnv[c]);
                if (s < run_s[r]) { run_s[r] = s; run_i[r] = kg; }
            }
        }
    }

    // ---- in-wave merge: butterfly over 16 cols; win + loss partials ----
    float bs = 0.f;
#pragma unroll
    for (int r = 0; r < 4; ++r) {
        float s = run_s[r]; int bi = run_i[r];
#pragma unroll
        for (int mask = 1; mask < 16; mask <<= 1) {
            float os = __shfl_xor(s, mask);
            int   oi = __shfl_xor(bi, mask);
            if (os < s || (os == s && oi < bi)) { s = os; bi = oi; }
        }
        if (l15 == 0) {
            win[(w << 4) + (lg << 2) + r] = bi;    // C row = lg*4 + reg
            bs += s;
        }
    }
    {
        float v = ((l15 == 0) ? bs : 0.f) + rn;
#pragma unroll
        for (int m = 1; m < 64; m <<= 1) v += __shfl_xor(v, m);
        if (lane == 0) rs[w] = v;
    }
    __syncthreads();
    if (t == 0) {
        float v = rs[0] + rs[1] + rs[2] + rs[3] + rs[4] + rs[5] + rs[6] + rs[7];
        atomicAdd(loss, v * LOSS_SCALE);
    }

    // ---- gather q = emb[k*] fp32, store [B,D,H,W] coalesced ----
    {
        const int rowl = t & 127, dg = t >> 7;      // 4 dgrps x 32 d
        const int bi = win[rowl];
        const float4* eg = (const float4*)(emb + ((size_t)bi << 7) + (dg << 5));
        float* ob = outq + ((size_t)b << 17) + ((size_t)(dg << 5) << 10) + hw0 + rowl;
#pragma unroll
        for (int jj = 0; jj < 8; ++jj) {
            float4 v = eg[jj];
            ob[(size_t)(jj * 4 + 0) << 10] = v.x;
            ob[(size_t)(jj * 4 + 1) << 10] = v.y;
            ob[(size_t)(jj * 4 + 2) << 10] = v.z;
            ob[(size_t)(jj * 4 + 3) << 10] = v.w;
        }
    }
}

extern "C" void kernel_launch(void* const* d_in, const int* in_sizes, int n_in,
                              void* d_out, int out_size, void* d_ws, size_t ws_size,
                              hipStream_t stream) {
    const float* lat = (const float*)d_in[0];   // [32,128,32,32]
    const float* emb = (const float*)d_in[1];   // [1024,128]
    float* out = (float*)d_out;                 // q (4194304) + vq_loss (1)
    char* ws = (char*)d_ws;
    char*  E    = ws + WS_E;
    float* cn   = (float*)(ws + WS_C);
    float* loss = out + 4194304;

    k_prep <<<64,  256, 0, stream>>>(emb, E, cn, loss);
    k_fused<<<256, 512, 0, stream>>>(lat, emb, E, cn, out, loss);
}